// Round 8
// baseline (399.865 us; speedup 1.0000x reference)
//
#include <hip/hip_runtime.h>
#include <math.h>

#define B_ 8
#define P_ 1024
#define N_ 32
#define L_ 125
#define H_ 256
#define E_ 128
#define MT 128            // points per block; 8 waves = 4 j-blocks x 2 m-blocks

static_assert(E_ == 3 + L_, "embed dim mismatch");

typedef _Float16 half8 __attribute__((ext_vector_type(8)));
typedef _Float16 half4v __attribute__((ext_vector_type(4)));
typedef float f32x16 __attribute__((ext_vector_type(16)));

// ---------------------------------------------------------------------------
// Z[b][n][j] += b0 (zs==0) + partial latent dot. 4-way K-split over l.
// Z must be zeroed before launch (memset in kernel_launch).
// ---------------------------------------------------------------------------
__global__ void z_precompute(const float* __restrict__ latents,
                             const float* __restrict__ W0,
                             const float* __restrict__ b0,
                             float* __restrict__ Z) {
  const int b = blockIdx.x;
  const int n = blockIdx.y;
  const int zs = blockIdx.z;            // 0..3, l-range [32*zs, min(32*zs+32,125))
  const int j = threadIdx.x;
  const int l0 = zs * 32;
  const int nl = (l0 + 32 <= L_) ? 32 : (L_ - l0);
  __shared__ float lat[32];
  if (j < nl) lat[j] = latents[(n * B_ + b) * L_ + l0 + j];
  __syncthreads();
  const float* w0 = W0 + ((size_t)n * E_ + 3 + l0) * H_ + j;
  float acc = (zs == 0) ? b0[n * H_ + j] : 0.f;
  for (int l = 0; l < nl; ++l)
    acc = fmaf(lat[l], w0[(size_t)l * H_], acc);
  atomicAdd(&Z[(b * N_ + n) * H_ + j], acc);
}

// ---------------------------------------------------------------------------
// Transpose + hi/lo f16 split of W1,W2: WT[layer][node][j_out][h_in].
// ---------------------------------------------------------------------------
__global__ void wsplit(const float* __restrict__ W1, const float* __restrict__ W2,
                       _Float16* __restrict__ WThi, _Float16* __restrict__ WTlo) {
  const int node = blockIdx.x;
  const int layer = blockIdx.y;
  const int jb = blockIdx.z;            // 0..3: 64-wide j slice
  const float* W = (layer == 0 ? W1 : W2) + (size_t)node * H_ * H_;
  _Float16* dhi = WThi + ((size_t)layer * N_ + node) * H_ * H_;
  _Float16* dlo = WTlo + ((size_t)layer * N_ + node) * H_ * H_;
  __shared__ float tile[64][65];
  const int t = threadIdx.x;
  for (int hb = 0; hb < 4; ++hb) {
#pragma unroll
    for (int i = 0; i < 16; ++i) {
      const int row = (t >> 6) + 4 * i;
      const int col = t & 63;
      tile[row][col] = W[(size_t)(hb * 64 + row) * H_ + jb * 64 + col];
    }
    __syncthreads();
    {
      const int j_l = t >> 2;           // 0..63
      const int h0 = (t & 3) * 16;      // 0,16,32,48
      half8 hv0, hv1, lv0, lv1;
#pragma unroll
      for (int q = 0; q < 16; ++q) {
        const float v = tile[h0 + q][j_l];
        const _Float16 hh = (_Float16)v;
        const _Float16 ll = (_Float16)(v - (float)hh);
        if (q < 8) { hv0[q] = hh; lv0[q] = ll; }
        else       { hv1[q - 8] = hh; lv1[q - 8] = ll; }
      }
      const size_t off = (size_t)(jb * 64 + j_l) * H_ + hb * 64 + h0;
      *(half8*)(dhi + off) = hv0;
      *(half8*)(dhi + off + 8) = hv1;
      *(half8*)(dlo + off) = lv0;
      *(half8*)(dlo + off + 8) = lv1;
    }
    __syncthreads();
  }
}

// ---------------------------------------------------------------------------
// Main fused kernel. 2048 blocks; block decodes (node, ptile) XCD-aware.
// Block = 128 points x 1 node, 512 thr = 8 waves = 4 j-blocks(64) x 2 m-blocks(64).
// Wave computes C^T[64 j][64 m] via 32x32x16 f16 MFMA, 3-term split (hh+hl+lh).
// h LDS layout: [m][k] halves, 512-B rows, byte XOR ((m&31)<<4) full rotation
// -> every GEMM ds_read_b128 is 2 lanes/slot (free, m136); epilogue b64 writes
// land on disjoint banks. LDS 130 KB -> 1 block/CU, 2 waves/SIMD,
// launch_bounds(512,2) -> VGPR cap 256 (r7's 64-cap killed load ILP).
// ---------------------------------------------------------------------------
__global__ __launch_bounds__(512, 2)
void mlp_main(const float* __restrict__ X,
              const float* __restrict__ constants,
              const float* __restrict__ scales,
              const float* __restrict__ rotations,
              const float* __restrict__ centers,
              const float* __restrict__ W0,
              const float* __restrict__ b1,
              const float* __restrict__ b2,
              const float* __restrict__ Wout,
              const float* __restrict__ bout,
              const float* __restrict__ Z,
              const _Float16* __restrict__ WThi,
              const _Float16* __restrict__ WTlo,
              const int* __restrict__ use_constants,
              float* __restrict__ accum) {
  __shared__ _Float16 h_hi[MT * H_];   // 64 KB, [m][k] swizzled
  __shared__ _Float16 h_lo[MT * H_];   // 64 KB
  __shared__ float loc[MT][3];
  __shared__ float wgt[MT];
  __shared__ float predpart[MT];

  const int ell = blockIdx.x;
  const int node = (ell & 7) * 4 + ((ell >> 3) & 3);  // xcd*4 + q
  const int p0 = (ell >> 5) * MT;       // 64 ptiles
  const int b = p0 >> 10;               // P_ == 1024
  const int tid = threadIdx.x;
  const int lane = tid & 63;
  const int w = tid >> 6;
  const int lc = lane & 31;             // MFMA row/col within 32-tile
  const int kh = lane >> 5;             // k-half (8 k's each)
  const int jb = w & 3;                 // j-block (64 j)
  const int mb = w >> 2;                // m-block (64 m)

  if (tid < MT) {
    predpart[tid] = 0.f;
    const int t = tid;
    const int pidx = p0 + t;
    const float x0 = X[pidx * 3 + 0];
    const float x1 = X[pidx * 3 + 1];
    const float x2 = X[pidx * 3 + 2];
    const float* R = rotations + (size_t)(b * N_ + node) * 9;
    const float* C = centers + (size_t)(b * N_ + node) * 3;
    const float* S = scales + (size_t)(b * N_ + node) * 3;
    const float d0 = x0 - C[0], d1 = x1 - C[1], d2 = x2 - C[2];
    const float l0 = (R[0] * d0 + R[1] * d1 + R[2] * d2) / S[0];
    const float l1 = (R[3] * d0 + R[4] * d1 + R[5] * d2) / S[1];
    const float l2 = (R[6] * d0 + R[7] * d1 + R[8] * d2) / S[2];
    loc[t][0] = l0; loc[t][1] = l1; loc[t][2] = l2;
    float ww = expf(-0.5f * (l0 * l0 + l1 * l1 + l2 * l2));
    if (use_constants[0] != 0) ww *= constants[b * N_ + node];
    wgt[t] = ww;
  }
  __syncthreads();

  // ---- layer 0: 4 threads per point m, 64 j's each; swizzled b64 writes ----
  {
    const int m = tid & 127;
    const int jr = (tid >> 7) * 64;
    const float l0 = loc[m][0], l1 = loc[m][1], l2 = loc[m][2];
    const float* w0p = W0 + (size_t)node * E_ * H_;
    const float* zp = Z + (size_t)(b * N_ + node) * H_;
    char* hh = (char*)h_hi + m * 512;
    char* hl = (char*)h_lo + m * 512;
    const int xr = (m & 31) << 4;
#pragma unroll
    for (int j = jr; j < jr + 64; j += 4) {
      const float4 a0 = *(const float4*)(w0p + j);
      const float4 a1 = *(const float4*)(w0p + H_ + j);
      const float4 a2 = *(const float4*)(w0p + 2 * H_ + j);
      const float4 zz = *(const float4*)(zp + j);
      float v[4];
      v[0] = fmaxf(fmaf(l2, a2.x, fmaf(l1, a1.x, fmaf(l0, a0.x, zz.x))), 0.f);
      v[1] = fmaxf(fmaf(l2, a2.y, fmaf(l1, a1.y, fmaf(l0, a0.y, zz.y))), 0.f);
      v[2] = fmaxf(fmaf(l2, a2.z, fmaf(l1, a1.z, fmaf(l0, a0.z, zz.z))), 0.f);
      v[3] = fmaxf(fmaf(l2, a2.w, fmaf(l1, a1.w, fmaf(l0, a0.w, zz.w))), 0.f);
      half4v hv, lv;
#pragma unroll
      for (int r = 0; r < 4; ++r) {
        const _Float16 h16 = (_Float16)v[r];
        hv[r] = h16;
        lv[r] = (_Float16)(v[r] - (float)h16);
      }
      const int off = (j * 2) ^ xr;
      *(half4v*)(hh + off) = hv;
      *(half4v*)(hl + off) = lv;
    }
  }
  __syncthreads();

  f32x16 acc[2][2];   // [jt][mt], each 32x32 tile

  const _Float16* wt1hi = WThi + (size_t)node * H_ * H_;
  const _Float16* wt1lo = WTlo + (size_t)node * H_ * H_;
  const _Float16* wt2hi = WThi + ((size_t)N_ + node) * H_ * H_;
  const _Float16* wt2lo = WTlo + ((size_t)N_ + node) * H_ * H_;

  const int xr = lc << 4;

  auto run_layer = [&](const _Float16* __restrict__ whi,
                       const _Float16* __restrict__ wlo) {
#pragma unroll
    for (int jt = 0; jt < 2; ++jt)
#pragma unroll
      for (int mt = 0; mt < 2; ++mt) acc[jt][mt] = (f32x16)(0.f);
    const _Float16* wh0 = whi + (size_t)(jb * 64 + lc) * H_ + kh * 8;
    const _Float16* wl0 = wlo + (size_t)(jb * 64 + lc) * H_ + kh * 8;
    const char* bhp = (const char*)h_hi + (mb * 64 + lc) * 512;
    const char* blp = (const char*)h_lo + (mb * 64 + lc) * 512;
#pragma unroll
    for (int kc = 0; kc < 16; ++kc) {
      const half8 a_h0 = *(const half8*)(wh0 + kc * 16);
      const half8 a_h1 = *(const half8*)(wh0 + 32 * H_ + kc * 16);
      const half8 a_l0 = *(const half8*)(wl0 + kc * 16);
      const half8 a_l1 = *(const half8*)(wl0 + 32 * H_ + kc * 16);
      const int ko = (kc * 32 + kh * 16) ^ xr;
      const half8 b_h0 = *(const half8*)(bhp + ko);
      const half8 b_h1 = *(const half8*)(bhp + 32 * 512 + ko);
      const half8 b_l0 = *(const half8*)(blp + ko);
      const half8 b_l1 = *(const half8*)(blp + 32 * 512 + ko);
      acc[0][0] = __builtin_amdgcn_mfma_f32_32x32x16_f16(a_h0, b_h0, acc[0][0], 0, 0, 0);
      acc[0][0] = __builtin_amdgcn_mfma_f32_32x32x16_f16(a_h0, b_l0, acc[0][0], 0, 0, 0);
      acc[0][0] = __builtin_amdgcn_mfma_f32_32x32x16_f16(a_l0, b_h0, acc[0][0], 0, 0, 0);
      acc[0][1] = __builtin_amdgcn_mfma_f32_32x32x16_f16(a_h0, b_h1, acc[0][1], 0, 0, 0);
      acc[0][1] = __builtin_amdgcn_mfma_f32_32x32x16_f16(a_h0, b_l1, acc[0][1], 0, 0, 0);
      acc[0][1] = __builtin_amdgcn_mfma_f32_32x32x16_f16(a_l0, b_h1, acc[0][1], 0, 0, 0);
      acc[1][0] = __builtin_amdgcn_mfma_f32_32x32x16_f16(a_h1, b_h0, acc[1][0], 0, 0, 0);
      acc[1][0] = __builtin_amdgcn_mfma_f32_32x32x16_f16(a_h1, b_l0, acc[1][0], 0, 0, 0);
      acc[1][0] = __builtin_amdgcn_mfma_f32_32x32x16_f16(a_l1, b_h0, acc[1][0], 0, 0, 0);
      acc[1][1] = __builtin_amdgcn_mfma_f32_32x32x16_f16(a_h1, b_h1, acc[1][1], 0, 0, 0);
      acc[1][1] = __builtin_amdgcn_mfma_f32_32x32x16_f16(a_h1, b_l1, acc[1][1], 0, 0, 0);
      acc[1][1] = __builtin_amdgcn_mfma_f32_32x32x16_f16(a_l1, b_h1, acc[1][1], 0, 0, 0);
    }
  };

  // ---- layer 1 ----
  run_layer(wt1hi, wt1lo);
  __syncthreads();   // all waves done reading h0
  {
#pragma unroll
    for (int jt = 0; jt < 2; ++jt) {
#pragma unroll
      for (int q = 0; q < 4; ++q) {
        const int jq = jb * 64 + jt * 32 + 8 * q + 4 * kh;   // j = jq + r
        const float4 bb = *(const float4*)(b1 + node * H_ + jq);
        const float bv[4] = {bb.x, bb.y, bb.z, bb.w};
#pragma unroll
        for (int mt = 0; mt < 2; ++mt) {
          half4v hv, lv;
#pragma unroll
          for (int r = 0; r < 4; ++r) {
            const float v = fmaxf(acc[jt][mt][4 * q + r] + bv[r], 0.f);
            const _Float16 h16 = (_Float16)v;
            hv[r] = h16;
            lv[r] = (_Float16)(v - (float)h16);
          }
          const int m = mb * 64 + mt * 32 + lc;
          const int off = (jq * 2) ^ xr;
          *(half4v*)((char*)h_hi + m * 512 + off) = hv;
          *(half4v*)((char*)h_lo + m * 512 + off) = lv;
        }
      }
    }
  }
  __syncthreads();

  // ---- layer 2 + fused Wout ----
  run_layer(wt2hi, wt2lo);
  {
    float s0 = 0.f, s1 = 0.f;
#pragma unroll
    for (int jt = 0; jt < 2; ++jt) {
#pragma unroll
      for (int q = 0; q < 4; ++q) {
        const int jq = jb * 64 + jt * 32 + 8 * q + 4 * kh;
        const float4 bb = *(const float4*)(b2 + node * H_ + jq);
        const float4 wo = *(const float4*)(Wout + node * H_ + jq);
        const float bv[4] = {bb.x, bb.y, bb.z, bb.w};
        const float wv[4] = {wo.x, wo.y, wo.z, wo.w};
#pragma unroll
        for (int r = 0; r < 4; ++r) {
          s0 = fmaf(fmaxf(acc[jt][0][4 * q + r] + bv[r], 0.f), wv[r], s0);
          s1 = fmaf(fmaxf(acc[jt][1][4 * q + r] + bv[r], 0.f), wv[r], s1);
        }
      }
    }
    s0 += __shfl_xor(s0, 32, 64);   // combine the two k-half j-sets (same m)
    s1 += __shfl_xor(s1, 32, 64);
    if (lane < 32) {
      atomicAdd(&predpart[mb * 64 + lc], s0);
      atomicAdd(&predpart[mb * 64 + 32 + lc], s1);
    }
  }
  __syncthreads();

  if (tid < MT) {
    atomicAdd(&accum[p0 + tid], wgt[tid] * (predpart[tid] + bout[node] + 0.5f));
  }
}

// ---------------------------------------------------------------------------
__global__ void finalize(const float* __restrict__ accum, float* __restrict__ out) {
  const int i = blockIdx.x * 256 + threadIdx.x;
  const float v = accum[i];
  out[i] = v;
  const float zz = 100.0f * (-0.07f - v);
  out[B_ * P_ + i] = 1.0f / (1.0f + expf(-zz));
}

// ---------------------------------------------------------------------------
extern "C" void kernel_launch(void* const* d_in, const int* in_sizes, int n_in,
                              void* d_out, int out_size, void* d_ws, size_t ws_size,
                              hipStream_t stream) {
  const float* X = (const float*)d_in[0];
  const float* latents = (const float*)d_in[1];
  const float* constants = (const float*)d_in[2];
  const float* scales = (const float*)d_in[3];
  const float* rotations = (const float*)d_in[4];
  const float* centers = (const float*)d_in[5];
  const float* W0 = (const float*)d_in[6];
  const float* b0 = (const float*)d_in[7];
  const float* W1 = (const float*)d_in[8];
  const float* b1 = (const float*)d_in[9];
  const float* W2 = (const float*)d_in[10];
  const float* b2 = (const float*)d_in[11];
  const float* Wout = (const float*)d_in[12];
  const float* bout = (const float*)d_in[13];
  const int* use_constants = (const int*)d_in[14];

  float* accum = (float*)d_ws;                       // 8192 f32
  float* Zbuf = accum + B_ * P_;                     // 65536 f32 (contiguous)
  _Float16* WThi = (_Float16*)(Zbuf + B_ * N_ * H_); // 8 MB
  _Float16* WTlo = WThi + (size_t)2 * N_ * H_ * H_;  // 8 MB

  hipMemsetAsync(accum, 0, (B_ * P_ + B_ * N_ * H_) * sizeof(float), stream);

  z_precompute<<<dim3(B_, N_, 4), 256, 0, stream>>>(latents, W0, b0, Zbuf);
  wsplit<<<dim3(N_, 2, 4), 256, 0, stream>>>(W1, W2, WThi, WTlo);

  mlp_main<<<dim3(B_ * P_ / MT * N_), 512, 0, stream>>>(
      X, constants, scales, rotations, centers, W0, b1, b2, Wout, bout,
      Zbuf, WThi, WTlo, use_constants, accum);

  finalize<<<dim3(B_ * P_ / 256), 256, 0, stream>>>(accum, (float*)d_out);
}

// Round 9
// 287.711 us; speedup vs baseline: 1.3898x; 1.3898x over previous
//
#include <hip/hip_runtime.h>
#include <math.h>

#define B_ 8
#define P_ 1024
#define N_ 32
#define L_ 125
#define H_ 256
#define E_ 128
#define MT 64             // points per block; 8 waves, wave w owns j in [32w,32w+32)

static_assert(E_ == 3 + L_, "embed dim mismatch");

typedef _Float16 half8 __attribute__((ext_vector_type(8)));
typedef _Float16 half4v __attribute__((ext_vector_type(4)));
typedef float f32x16 __attribute__((ext_vector_type(16)));

// ---------------------------------------------------------------------------
// Z[b][n][j] += b0 (zs==0) + partial latent dot over l-range [32zs, ...).
// Grid (N,4): W0 slice read ONCE, all 8 batches accumulated in registers.
// Z must be zeroed before launch.
// ---------------------------------------------------------------------------
__global__ void z_precompute(const float* __restrict__ latents,
                             const float* __restrict__ W0,
                             const float* __restrict__ b0,
                             float* __restrict__ Z) {
  const int n = blockIdx.x, zs = blockIdx.y;
  const int l0 = zs * 32;
  const int nl = (l0 + 32 <= L_) ? 32 : (L_ - l0);
  __shared__ float lat[B_][32];
  const int t = threadIdx.x;            // 256 = H
  {
    const int b = t >> 5, l = t & 31;
    lat[b][l] = (l < nl) ? latents[(n * B_ + b) * L_ + l0 + l] : 0.f;
  }
  __syncthreads();
  const float* w0 = W0 + ((size_t)n * E_ + 3 + l0) * H_ + t;
  float acc[B_];
#pragma unroll
  for (int b = 0; b < B_; ++b) acc[b] = 0.f;
  for (int l = 0; l < nl; ++l) {
    const float wv = w0[(size_t)l * H_];
#pragma unroll
    for (int b = 0; b < B_; ++b) acc[b] = fmaf(lat[b][l], wv, acc[b]);
  }
  const float base = (zs == 0) ? b0[n * H_ + t] : 0.f;
#pragma unroll
  for (int b = 0; b < B_; ++b)
    atomicAdd(&Z[(b * N_ + n) * H_ + t], acc[b] + base);
}

// ---------------------------------------------------------------------------
// Transpose + hi/lo f16 split of W1,W2 directly into MFMA FRAGMENT order:
//   WT[layer][node][w(8)][kc(16)][kh(2)][lc(32)][8 halves]
// so a wave's A-load (lane (lc,kh), step kc) is 1024 contiguous bytes.
// Grid (N, 2, 16): one 64k x 64j tile per block.
// ---------------------------------------------------------------------------
__global__ void wsplit(const float* __restrict__ W1, const float* __restrict__ W2,
                       _Float16* __restrict__ WThi, _Float16* __restrict__ WTlo) {
  const int node = blockIdx.x;
  const int layer = blockIdx.y;
  const int jb = blockIdx.z >> 2;       // 0..3: 64-wide j slice
  const int kb = blockIdx.z & 3;        // 0..3: 64-wide k slice
  const float* W = (layer == 0 ? W1 : W2) + (size_t)node * H_ * H_;
  _Float16* dhi = WThi + ((size_t)layer * N_ + node) * H_ * H_;
  _Float16* dlo = WTlo + ((size_t)layer * N_ + node) * H_ * H_;
  __shared__ float tile[64][65];        // [k][j]
  const int t = threadIdx.x;            // 256
  {
    const int col = t & 63;
#pragma unroll
    for (int i = 0; i < 16; ++i) {
      const int row = (t >> 6) * 16 + i;
      tile[row][col] = W[(size_t)(kb * 64 + row) * H_ + jb * 64 + col];
    }
  }
  __syncthreads();
  const int j_l = t >> 2;               // 0..63
  const int j = jb * 64 + j_l;
  const int w = j >> 5, lc = j & 31;
  const int kq = (t & 3) * 16;          // 16 consecutive k = one kc (kh 0+1)
  const int kc = kb * 4 + (t & 3);
  half8 hv0, hv1, lv0, lv1;
#pragma unroll
  for (int q = 0; q < 16; ++q) {
    const float v = tile[kq + q][j_l];
    const _Float16 hh = (_Float16)v;
    const _Float16 ll = (_Float16)(v - (float)hh);
    if (q < 8) { hv0[q] = hh; lv0[q] = ll; }
    else       { hv1[q - 8] = hh; lv1[q - 8] = ll; }
  }
  const size_t o0 = (size_t)w * 8192 + (size_t)kc * 512 + lc * 8;  // kh=0
  const size_t o1 = o0 + 256;                                       // kh=1
  *(half8*)(dhi + o0) = hv0;
  *(half8*)(dhi + o1) = hv1;
  *(half8*)(dlo + o0) = lv0;
  *(half8*)(dlo + o1) = lv1;
}

// ---------------------------------------------------------------------------
// Main fused kernel. 4096 blocks; (node, ptile) XCD-aware decode.
// Block = 64 points x 1 node, 512 thr = 8 waves; wave w owns j in [32w,32w+32),
// computes C^T[32j x 64m] = 2 x 32x32 tiles via 32x32x16 f16 MFMA, 3-term split.
// h LDS [m][k]: 512-B rows, 16-B slot index (k/8) ^ (m&31)  ->  all GEMM
// ds_read_b128 and all epilogue b64 writes are <=2 lanes/bank-group (free).
// A (weights) read from global in fragment order (coalesced 1024 B / wave),
// 1-deep explicit prefetch. LDS 66 KB -> 2 blocks/CU = 4 waves/SIMD;
// launch_bounds(512,4) -> 128 VGPR cap.
// ---------------------------------------------------------------------------
__global__ __launch_bounds__(512, 4)
void mlp_main(const float* __restrict__ X,
              const float* __restrict__ constants,
              const float* __restrict__ scales,
              const float* __restrict__ rotations,
              const float* __restrict__ centers,
              const float* __restrict__ W0,
              const float* __restrict__ b1,
              const float* __restrict__ b2,
              const float* __restrict__ Wout,
              const float* __restrict__ bout,
              const float* __restrict__ Z,
              const _Float16* __restrict__ WThi,
              const _Float16* __restrict__ WTlo,
              const int* __restrict__ use_constants,
              float* __restrict__ accum) {
  __shared__ _Float16 h_hi[MT * H_];   // 32 KB
  __shared__ _Float16 h_lo[MT * H_];   // 32 KB
  __shared__ float loc[MT][3];
  __shared__ float wgt[MT];
  __shared__ float predpart[MT];

  const int ell = blockIdx.x;
  const int node = (ell & 7) * 4 + ((ell >> 3) & 3);  // xcd*4 + q
  const int p0 = (ell >> 5) * MT;       // 128 ptiles
  const int b = p0 >> 10;               // P_ == 1024
  const int tid = threadIdx.x;
  const int lane = tid & 63;
  const int w = tid >> 6;
  const int lc = lane & 31;
  const int kh = lane >> 5;

  if (tid < MT) {
    predpart[tid] = 0.f;
    const int pidx = p0 + tid;
    const float x0 = X[pidx * 3 + 0];
    const float x1 = X[pidx * 3 + 1];
    const float x2 = X[pidx * 3 + 2];
    const float* R = rotations + (size_t)(b * N_ + node) * 9;
    const float* C = centers + (size_t)(b * N_ + node) * 3;
    const float* S = scales + (size_t)(b * N_ + node) * 3;
    const float d0 = x0 - C[0], d1 = x1 - C[1], d2 = x2 - C[2];
    const float l0 = (R[0] * d0 + R[1] * d1 + R[2] * d2) / S[0];
    const float l1 = (R[3] * d0 + R[4] * d1 + R[5] * d2) / S[1];
    const float l2 = (R[6] * d0 + R[7] * d1 + R[8] * d2) / S[2];
    loc[tid][0] = l0; loc[tid][1] = l1; loc[tid][2] = l2;
    float ww = expf(-0.5f * (l0 * l0 + l1 * l1 + l2 * l2));
    if (use_constants[0] != 0) ww *= constants[b * N_ + node];
    wgt[tid] = ww;
  }
  __syncthreads();

  // ---- layer 0: lane owns point m=lane; wave w covers j in [32w,32w+32).
  // W0/Z loads are wave-uniform (scalar broadcast). Swizzled 8-B writes.
  {
    const int m = lane;
    const float l0 = loc[m][0], l1 = loc[m][1], l2 = loc[m][2];
    const float* w0p = W0 + (size_t)node * E_ * H_;
    const float* zp = Z + (size_t)(b * N_ + node) * H_;
    char* hhp = (char*)h_hi + m * 512;
    char* hlp = (char*)h_lo + m * 512;
    const int mx = m & 31;
#pragma unroll
    for (int j = w * 32; j < w * 32 + 32; j += 4) {
      const float4 a0 = *(const float4*)(w0p + j);
      const float4 a1 = *(const float4*)(w0p + H_ + j);
      const float4 a2 = *(const float4*)(w0p + 2 * H_ + j);
      const float4 zz = *(const float4*)(zp + j);
      float v[4];
      v[0] = fmaxf(fmaf(l2, a2.x, fmaf(l1, a1.x, fmaf(l0, a0.x, zz.x))), 0.f);
      v[1] = fmaxf(fmaf(l2, a2.y, fmaf(l1, a1.y, fmaf(l0, a0.y, zz.y))), 0.f);
      v[2] = fmaxf(fmaf(l2, a2.z, fmaf(l1, a1.z, fmaf(l0, a0.z, zz.z))), 0.f);
      v[3] = fmaxf(fmaf(l2, a2.w, fmaf(l1, a1.w, fmaf(l0, a0.w, zz.w))), 0.f);
      half4v hv, lv;
#pragma unroll
      for (int r = 0; r < 4; ++r) {
        const _Float16 h16 = (_Float16)v[r];
        hv[r] = h16;
        lv[r] = (_Float16)(v[r] - (float)h16);
      }
      const int off = (((j >> 3) ^ mx) << 4) + ((j & 7) << 1);
      *(half4v*)(hhp + off) = hv;
      *(half4v*)(hlp + off) = lv;
    }
  }
  __syncthreads();

  f32x16 acc0, acc1;   // mt=0 (m 0..31), mt=1 (m 32..63)

  const size_t wb = (size_t)node * H_ * H_ + (size_t)w * 8192 + (kh * 32 + lc) * 8;
  const _Float16* wt1hi = WThi + wb;
  const _Float16* wt1lo = WTlo + wb;
  const _Float16* wt2hi = WThi + (size_t)N_ * H_ * H_ + wb;
  const _Float16* wt2lo = WTlo + (size_t)N_ * H_ * H_ + wb;

  const char* rbh0 = (const char*)h_hi + lc * 512;
  const char* rbh1 = (const char*)h_hi + (32 + lc) * 512;
  const char* rbl0 = (const char*)h_lo + lc * 512;
  const char* rbl1 = (const char*)h_lo + (32 + lc) * 512;

  auto run_layer = [&](const _Float16* __restrict__ wh,
                       const _Float16* __restrict__ wl) {
    acc0 = (f32x16)(0.f);
    acc1 = (f32x16)(0.f);
    half8 aH = *(const half8*)(wh);
    half8 aL = *(const half8*)(wl);
#pragma unroll
    for (int kc = 0; kc < 16; ++kc) {
      half8 aHn, aLn;
      if (kc < 15) {
        aHn = *(const half8*)(wh + (kc + 1) * 512);
        aLn = *(const half8*)(wl + (kc + 1) * 512);
      }
      const int so = ((2 * kc + kh) ^ lc) << 4;
      const half8 bh0 = *(const half8*)(rbh0 + so);
      const half8 bh1 = *(const half8*)(rbh1 + so);
      const half8 bl0 = *(const half8*)(rbl0 + so);
      const half8 bl1 = *(const half8*)(rbl1 + so);
      __builtin_amdgcn_s_setprio(1);
      acc0 = __builtin_amdgcn_mfma_f32_32x32x16_f16(aH, bh0, acc0, 0, 0, 0);
      acc0 = __builtin_amdgcn_mfma_f32_32x32x16_f16(aH, bl0, acc0, 0, 0, 0);
      acc0 = __builtin_amdgcn_mfma_f32_32x32x16_f16(aL, bh0, acc0, 0, 0, 0);
      acc1 = __builtin_amdgcn_mfma_f32_32x32x16_f16(aH, bh1, acc1, 0, 0, 0);
      acc1 = __builtin_amdgcn_mfma_f32_32x32x16_f16(aH, bl1, acc1, 0, 0, 0);
      acc1 = __builtin_amdgcn_mfma_f32_32x32x16_f16(aL, bh1, acc1, 0, 0, 0);
      __builtin_amdgcn_s_setprio(0);
      if (kc < 15) { aH = aHn; aL = aLn; }
    }
  };

  // ---- layer 1 ----
  run_layer(wt1hi, wt1lo);
  __syncthreads();   // all waves done reading h0
  {
#pragma unroll
    for (int q = 0; q < 4; ++q) {
      const int jq = 32 * w + 8 * q + 4 * kh;          // jq>>3 = 4w+q, jq&7 = 4kh
      const float4 bb = *(const float4*)(b1 + node * H_ + jq);
      const float bv[4] = {bb.x, bb.y, bb.z, bb.w};
      const int soff = ((((4 * w + q) ^ lc) << 4) + (kh << 3));
      half4v hv, lv;
#pragma unroll
      for (int r = 0; r < 4; ++r) {
        const float v = fmaxf(acc0[4 * q + r] + bv[r], 0.f);
        const _Float16 h16 = (_Float16)v;
        hv[r] = h16;
        lv[r] = (_Float16)(v - (float)h16);
      }
      *(half4v*)((char*)h_hi + lc * 512 + soff) = hv;
      *(half4v*)((char*)h_lo + lc * 512 + soff) = lv;
#pragma unroll
      for (int r = 0; r < 4; ++r) {
        const float v = fmaxf(acc1[4 * q + r] + bv[r], 0.f);
        const _Float16 h16 = (_Float16)v;
        hv[r] = h16;
        lv[r] = (_Float16)(v - (float)h16);
      }
      *(half4v*)((char*)h_hi + (32 + lc) * 512 + soff) = hv;
      *(half4v*)((char*)h_lo + (32 + lc) * 512 + soff) = lv;
    }
  }
  __syncthreads();

  // ---- layer 2 + fused Wout ----
  run_layer(wt2hi, wt2lo);
  {
    float s0 = 0.f, s1 = 0.f;
#pragma unroll
    for (int q = 0; q < 4; ++q) {
      const int jq = 32 * w + 8 * q + 4 * kh;
      const float4 bb = *(const float4*)(b2 + node * H_ + jq);
      const float4 wo = *(const float4*)(Wout + node * H_ + jq);
      const float bv[4] = {bb.x, bb.y, bb.z, bb.w};
      const float wv[4] = {wo.x, wo.y, wo.z, wo.w};
#pragma unroll
      for (int r = 0; r < 4; ++r) {
        s0 = fmaf(fmaxf(acc0[4 * q + r] + bv[r], 0.f), wv[r], s0);
        s1 = fmaf(fmaxf(acc1[4 * q + r] + bv[r], 0.f), wv[r], s1);
      }
    }
    s0 += __shfl_xor(s0, 32, 64);   // combine kh halves (same m)
    s1 += __shfl_xor(s1, 32, 64);
    if (lane < 32) {
      atomicAdd(&predpart[lc], s0);
      atomicAdd(&predpart[32 + lc], s1);
    }
  }
  __syncthreads();

  if (tid < MT)
    atomicAdd(&accum[p0 + tid], wgt[tid] * (predpart[tid] + bout[node] + 0.5f));
}

// ---------------------------------------------------------------------------
__global__ void finalize(const float* __restrict__ accum, float* __restrict__ out) {
  const int i = blockIdx.x * 256 + threadIdx.x;
  const float v = accum[i];
  out[i] = v;
  const float zz = 100.0f * (-0.07f - v);
  out[B_ * P_ + i] = 1.0f / (1.0f + expf(-zz));
}

// ---------------------------------------------------------------------------
extern "C" void kernel_launch(void* const* d_in, const int* in_sizes, int n_in,
                              void* d_out, int out_size, void* d_ws, size_t ws_size,
                              hipStream_t stream) {
  const float* X = (const float*)d_in[0];
  const float* latents = (const float*)d_in[1];
  const float* constants = (const float*)d_in[2];
  const float* scales = (const float*)d_in[3];
  const float* rotations = (const float*)d_in[4];
  const float* centers = (const float*)d_in[5];
  const float* W0 = (const float*)d_in[6];
  const float* b0 = (const float*)d_in[7];
  const float* W1 = (const float*)d_in[8];
  const float* b1 = (const float*)d_in[9];
  const float* W2 = (const float*)d_in[10];
  const float* b2 = (const float*)d_in[11];
  const float* Wout = (const float*)d_in[12];
  const float* bout = (const float*)d_in[13];
  const int* use_constants = (const int*)d_in[14];

  float* accum = (float*)d_ws;                       // 8192 f32
  float* Zbuf = accum + B_ * P_;                     // 65536 f32 (contiguous)
  _Float16* WThi = (_Float16*)(Zbuf + B_ * N_ * H_); // 8 MB
  _Float16* WTlo = WThi + (size_t)2 * N_ * H_ * H_;  // 8 MB

  hipMemsetAsync(accum, 0, (B_ * P_ + B_ * N_ * H_) * sizeof(float), stream);

  z_precompute<<<dim3(N_, 4), 256, 0, stream>>>(latents, W0, b0, Zbuf);
  wsplit<<<dim3(N_, 2, 16), 256, 0, stream>>>(W1, W2, WThi, WTlo);

  mlp_main<<<dim3(B_ * P_ / MT * N_), 512, 0, stream>>>(
      X, constants, scales, rotations, centers, W0, b1, b2, Wout, bout,
      Zbuf, WThi, WTlo, use_constants, accum);

  finalize<<<dim3(B_ * P_ / 256), 256, 0, stream>>>(accum, (float*)d_out);
}